// Round 4
// baseline (238.429 us; speedup 1.0000x reference)
//
#include <hip/hip_runtime.h>

// Problem constants (from reference setup_inputs): B=128, Q=500, C=80, T=64
#define BN 128
#define QN 500
#define CLS 80
#define TN 64
#define RPB 20                  // rows per cost block
#define CBI 25                  // cost blocks per image (500/20)
#define RPW 5                   // rows per wave (RPB/4), compile-time trip

typedef unsigned long long ull;

// Monotonic float->uint map: a < b  <=>  fkey(a) < fkey(b); equal <=> equal
__device__ __forceinline__ unsigned fkey(float x) {
    unsigned u = __float_as_uint(x);
    return (u & 0x80000000u) ? ~u : (u | 0x80000000u);
}
__device__ __forceinline__ ull kmin(ull a, ull b) { return a < b ? a : b; }  // branchless

// Full-wave (64-lane) u32 min via DPP: row_shr 1/2/4/8 + row_bcast15/31,
// identity 0xFFFFFFFF fed to invalid lanes; result in lane 63 -> readlane.
#define DPP_MIN_STEP(v, ctrl)                                                 \
    {                                                                         \
        unsigned _t = (unsigned)__builtin_amdgcn_update_dpp(                  \
            (int)0xFFFFFFFF, (int)(v), (ctrl), 0xf, 0xf, false);              \
        (v) = (_t < (v)) ? _t : (v);                                          \
    }
__device__ __forceinline__ unsigned wave_min_u32(unsigned v) {
    DPP_MIN_STEP(v, 0x111)   // row_shr:1
    DPP_MIN_STEP(v, 0x112)   // row_shr:2
    DPP_MIN_STEP(v, 0x114)   // row_shr:4
    DPP_MIN_STEP(v, 0x118)   // row_shr:8
    DPP_MIN_STEP(v, 0x142)   // row_bcast:15
    DPP_MIN_STEP(v, 0x143)   // row_bcast:31
    return (unsigned)__builtin_amdgcn_readlane((int)v, 63);
}

// Exact raveled argmin over 64 lanes holding (value hi, flat lo) pairs.
// Fast path: one 6-step u32 chain on hi; if the min value is held by a
// UNIQUE lane (overwhelming majority -- random float costs), the flat comes
// from a single variable-lane readlane. True value ties fall back to the
// second exact chain (min flat among tied lanes) == first-occurrence
// tie-break, identical semantics to the proven dual-chain version.
__device__ __forceinline__ ull wave_argmin(unsigned hi, unsigned lo) {
    const unsigned bv = wave_min_u32(hi);                  // min value (uniform)
    const ull tie = __ballot(hi == bv);
    unsigned fl;
    if (__popcll(tie) == 1) {                              // unique holder
        fl = (unsigned)__builtin_amdgcn_readlane(
            (int)lo, (int)(__ffsll((long long)tie) - 1));
    } else {                                               // rare: exact chain
        fl = wave_min_u32((hi == bv) ? lo : 0xFFFFFFFFu);
    }
    return ((ull)bv << 32) | fl;
}

// ---------------------------------------------------------------------------
// Greedy hot loop (single wave; lane = column) — proven in round 3.
// m1[j] = min alive key of column j. Per iteration: u32 value chain +
// ballot/ff1/readlane argmin (exact-tie fallback), per-lane 8-bit deadmask
// (lane l owns rows l+64k), cooperative column rescan on champion-row death
// (~4.6 per image).
// ---------------------------------------------------------------------------
__device__ __forceinline__ void greedy_loop(
    const float* __restrict__ Cb, ull m1in, int b, int lane,
    float* __restrict__ out_rows, float* __restrict__ out_cols)
{
    unsigned m1hi = (unsigned)(m1in >> 32);    // column-min value key
    unsigned m1lo = (unsigned)m1in;            // column-min flat index
    // lane l owns rows l, l+64, ..., l+448; bit k = row l+64k dead.
    // Rows 500..511 (rescan over-range; reads stay inside d_out) pre-dead:
    // 500 = 7*64+52 -> lanes 52..63 bit 7.
    unsigned deadmask = (lane >= 52) ? 0x80u : 0u;

    int my_i = 0, my_j = 0;             // lane t captures iteration t's result

    for (int t = 0; t < TN; ++t) {
        const ull best = wave_argmin(m1hi, m1lo);          // uniform
        const unsigned flat = (unsigned)best;
        const int i = (int)(flat >> 6);                    // SGPR
        const int j = (int)(flat & 63u);                   // SGPR
        if (lane == t) { my_i = i; my_j = j; }             // cmp + 2 cndmask

        if (lane == j) { m1hi = 0xFFFFFFFFu; m1lo = 0xFFFFFFFFu; }  // retire col
        deadmask |= (lane == (i & 63)) ? (1u << (i >> 6)) : 0u;     // retire row

        // stale champions (argmin row == i) rescan; INF m1 auto-excluded
        // (lo=0xFFFFFFFF -> argrow 0x3FFFFFF never equals i<=511).
        ull need = __ballot((m1lo >> 6) == (unsigned)i);
        while (need) {                                     // ~4.6 total/image
            const int jr = (int)(__ffsll((long long)need) - 1);  // lane==column
            need &= need - 1;
            ull nb = ~0ull;
            #pragma unroll
            for (int k8 = 0; k8 < 8; ++k8) {
                int r = lane + (k8 << 6);
                float vv = Cb[(size_t)r * TN + jr];
                bool dead = (deadmask >> k8) & 1u;
                ull kk = dead ? ~0ull
                              : (((ull)fkey(vv) << 32) | (unsigned)(r * TN + jr));
                nb = kmin(nb, kk);
            }
            const ull nbest = wave_argmin((unsigned)(nb >> 32), (unsigned)nb);
            if (lane == jr) { m1hi = (unsigned)(nbest >> 32); m1lo = (unsigned)nbest; }
        }
    }

    out_rows[b * TN + lane] = (float)my_i;                 // coalesced
    out_cols[b * TN + lane] = (float)my_j;
}

// ---------------------------------------------------------------------------
// FUSED kernel: cost matrix + last-block-per-image greedy assignment.
// Cost phase is BYTE-IDENTICAL math to the passing round-1/3 kernel (same
// source positions -> same FMA contraction; fast-math / expression motion
// flips greedy ties -> round-5 failure). Wave-uniform divisions hoisted to
// LDS staging (bit-identical wherever computed; div never FMA-contracts).
// Logits stay direct per-element gathers (round-2's LDS staging measured
// ~5 us slower).
//
// Fusion (this round): per-image completion counter; the 25th-finishing
// block of an image merges the 25 partial colmin rows and runs greedy
// INLINE, overlapping other images' cost work. Removes the standalone
// assign dispatch (~12 us: launch + fully-exposed serial latency); only
// the last image's greedy tail stays serial.
// Cross-XCD ordering: producer = __syncthreads (per-wave vmcnt drain) +
// __threadfence (device release, L2 writeback) + atomicAdd; consumer =
// atomicAdd ticket==24 + __threadfence (acquire, invalidate) then read.
// ---------------------------------------------------------------------------
__global__ __launch_bounds__(256) void cost_fused(
    const float* __restrict__ logits,   // [B,Q,C]
    const float* __restrict__ boxes,    // [B,Q,4]
    const int*   __restrict__ ids,      // [B,T]
    const float* __restrict__ tboxes,   // [B,T,4]
    const float* __restrict__ img,      // [B,4]
    float* __restrict__ Cout,           // [B,Q,T]
    ull* __restrict__ partial,          // [B*CBI, 64] colmin keys, or null
    int* __restrict__ cnt,              // [B] completion counters (zeroed), or null
    float* __restrict__ out_rows,       // [B,T]
    float* __restrict__ out_cols)       // [B,T]
{
    const int b    = blockIdx.x / CBI;
    const int blk  = blockIdx.x % CBI;
    const int wave = threadIdx.x >> 6;
    const int lane = threadIdx.x & 63;   // = column t
    const int q0   = blk * RPB;

    __shared__ float4 s_pb[RPB];        // raw pred boxes (this block's 20 rows)
    __shared__ float4 s_bn[RPB];        // normalized pred boxes (pb/im)
    __shared__ float4 s_tb[TN];         // raw target boxes
    __shared__ float4 s_tn[TN];         // normalized target boxes (tb/im)
    __shared__ int    s_id[TN];         // target class ids

    // Staging: wave 0 handles targets, wave 1 (lanes 0..19) handles pred rows.
    // Divisions here are bit-identical to the per-element ones they replace.
    if (wave == 0) {
        const float4 im = *(const float4*)(img + b * 4);
        const float4 tb = *(const float4*)(tboxes + (size_t)(b * TN + lane) * 4);
        s_tb[lane] = tb;
        float4 tn;
        tn.x = tb.x / im.x; tn.y = tb.y / im.y;
        tn.z = tb.z / im.z; tn.w = tb.w / im.w;
        s_tn[lane] = tn;
        s_id[lane] = ids[b * TN + lane];
    } else if (wave == 1 && lane < RPB) {
        const float4 im = *(const float4*)(img + b * 4);
        const float4 pb = *(const float4*)(boxes + (size_t)(b * QN + q0 + lane) * 4);
        s_pb[lane] = pb;
        float4 bn;
        bn.x = pb.x / im.x; bn.y = pb.y / im.y;
        bn.z = pb.z / im.z; bn.w = pb.w / im.w;
        s_bn[lane] = bn;
    }
    __syncthreads();

    const float4 tb  = s_tb[lane];
    const float4 tn  = s_tn[lane];
    const int    id  = s_id[lane];
    // area_b: SAME expression/position as prior rounds (standalone mul,
    // multi-use, never contracted) -- preserves bit pattern.
    const float area_b = (tb.z - tb.x) * (tb.w - tb.y);

    ull colmin = ~0ull;
    #pragma unroll
    for (int rr = 0; rr < RPW; ++rr) {
        const int lr = wave * RPW + rr;       // local row 0..19
        const int q  = q0 + lr;
        const float x   = logits[(size_t)(b * QN + q) * CLS + id];
        const float4 pb = s_pb[lr];           // broadcast LDS read (no conflict)
        const float4 bn = s_bn[lr];

        float prob = 1.0f / (1.0f + expf(-x));
        float neg  = 0.75f * (prob * prob) * (-log1pf(1e-8f - prob));
        float pos  = 0.25f * ((1.0f - prob) * (1.0f - prob)) * (-logf(prob + 1e-8f));
        float cls  = pos - neg;

        float l1 = fabsf(bn.x - tn.x) + fabsf(bn.y - tn.y)
                 + fabsf(bn.z - tn.z) + fabsf(bn.w - tn.w);

        // area_a stays INSIDE the loop (single-use mul may be FMA-contracted
        // into `uni`; hoisting could change rounding -> greedy tie flip).
        float area_a = (pb.z - pb.x) * (pb.w - pb.y);
        float ltx = fmaxf(pb.x, tb.x), lty = fmaxf(pb.y, tb.y);
        float rbx = fminf(pb.z, tb.z), rby = fminf(pb.w, tb.w);
        float iw = fmaxf(rbx - ltx, 0.0f), ih = fmaxf(rby - lty, 0.0f);
        float inter = iw * ih;
        float uni   = area_a + area_b - inter;
        float iou   = inter / uni;
        float ex1 = fminf(pb.x, tb.x), ey1 = fminf(pb.y, tb.y);
        float ex2 = fmaxf(pb.z, tb.z), ey2 = fmaxf(pb.w, tb.w);
        float ew = fmaxf(ex2 - ex1, 0.0f), eh = fmaxf(ey2 - ey1, 0.0f);
        float enc = ew * eh;
        float giou = iou - (enc - uni) / enc;

        float cost = 5.0f * l1 + 2.0f * cls + 2.0f * (-giou);
        Cout[(size_t)(b * QN + q) * TN + lane] = cost;
        colmin = kmin(colmin, ((ull)fkey(cost) << 32) | (unsigned)(q * TN + lane));
    }

    if (!partial) return;               // fallback path: cost only

    // Block colmin merge -> own partial slot (no race).
    __shared__ ull pk[4][TN];
    pk[wave][lane] = colmin;
    __syncthreads();                    // also drains each wave's Cout stores
    if (wave == 0) {
        ull k = kmin(kmin(pk[0][lane], pk[1][lane]),
                     kmin(pk[2][lane], pk[3][lane]));
        partial[(size_t)blockIdx.x * TN + lane] = k;
    }

    // Last-block election. thread 0 is in wave 0: its fence waits vmcnt(0)
    // (covers wave 0's partial-slot stores; other waves' Cout stores were
    // drained at the barrier above) and writes back L2 (device release).
    __shared__ int s_ticket;
    if (threadIdx.x == 0) {
        __threadfence();
        s_ticket = atomicAdd(&cnt[b], 1);
    }
    __syncthreads();
    if (s_ticket != CBI - 1) return;    // not last: done
    if (wave != 0) return;              // greedy is single-wave

    __threadfence();                    // acquire: invalidate stale cache

    const ull* pt = partial + (size_t)b * CBI * TN;
    ull m1 = ~0ull;
    #pragma unroll
    for (int r = 0; r < CBI; ++r) m1 = kmin(m1, pt[(size_t)r * TN + lane]);

    greedy_loop(Cout + (size_t)b * QN * TN, m1, b, lane, out_rows, out_cols);
}

// Fallback path (no workspace): float4 init, branchless min, LDS merge.
// Wave w, lane l: g=l>>4 owns rows w*63+g+4k (k<16), c4=l&15 owns cols
// [4c4,4c4+4) -> 16 independent float4 loads/thread. Proven in round 9.
__global__ __launch_bounds__(512, 1) void assign_scan_kernel(
    const float* __restrict__ Cmat,
    float* __restrict__ out_rows, float* __restrict__ out_cols)
{
    const int b    = blockIdx.x;
    const int wave = threadIdx.x >> 6;
    const int lane = threadIdx.x & 63;
    const float* Cb = Cmat + (size_t)b * QN * TN;

    __shared__ ull smin[32][TN];        // 16 KB

    {
        const int g  = lane >> 4;
        const int c4 = (lane & 15) << 2;
        const int rbeg = wave * 63 + g;
        ull mc0 = ~0ull, mc1 = ~0ull, mc2 = ~0ull, mc3 = ~0ull;
        #pragma unroll
        for (int k = 0; k < 16; ++k) {
            const int r = rbeg + 4 * k;            // <= 504: inside d_out
            const float4 v = *(const float4*)(Cb + (size_t)r * TN + c4);
            const bool ok = (r < QN);
            const unsigned fb = (unsigned)(r * TN + c4);
            mc0 = kmin(mc0, ok ? (((ull)fkey(v.x) << 32) | (fb + 0)) : ~0ull);
            mc1 = kmin(mc1, ok ? (((ull)fkey(v.y) << 32) | (fb + 1)) : ~0ull);
            mc2 = kmin(mc2, ok ? (((ull)fkey(v.z) << 32) | (fb + 2)) : ~0ull);
            mc3 = kmin(mc3, ok ? (((ull)fkey(v.w) << 32) | (fb + 3)) : ~0ull);
        }
        const int lrow = (wave << 2) | g;
        smin[lrow][c4 + 0] = mc0;
        smin[lrow][c4 + 1] = mc1;
        smin[lrow][c4 + 2] = mc2;
        smin[lrow][c4 + 3] = mc3;
    }
    __syncthreads();
    if (wave != 0) return;

    ull m1 = ~0ull;
    #pragma unroll
    for (int w = 0; w < 32; ++w) m1 = kmin(m1, smin[w][lane]);

    greedy_loop(Cb, m1, b, lane, out_rows, out_cols);
}

extern "C" void kernel_launch(void* const* d_in, const int* in_sizes, int n_in,
                              void* d_out, int out_size, void* d_ws, size_t ws_size,
                              hipStream_t stream) {
    const float* logits = (const float*)d_in[0];   // [128,500,80]
    const float* boxes  = (const float*)d_in[1];   // [128,500,4]
    const int*   ids    = (const int*)d_in[2];     // [128,64]
    const float* tboxes = (const float*)d_in[3];   // [128,64,4]
    const float* img    = (const float*)d_in[4];   // [128,4]

    float* out  = (float*)d_out;
    float* Cmat = out;                              // 128*500*64 = 4,096,000
    float* rows = out + (size_t)BN * QN * TN;       // +8192
    float* cols = rows + BN * TN;                   // +8192

    const size_t table_bytes = (size_t)BN * CBI * TN * sizeof(ull);  // 1.6 MB
    const size_t need_bytes  = table_bytes + BN * sizeof(int);
    const bool use_table = (ws_size >= need_bytes);                   // host-constant

    if (use_table) {
        ull* partial = (ull*)d_ws;
        int* cnt = (int*)((char*)d_ws + table_bytes);
        hipMemsetAsync(cnt, 0, BN * sizeof(int), stream);  // ws is poisoned
        cost_fused<<<BN * CBI, 256, 0, stream>>>(logits, boxes, ids, tboxes, img,
                                                 Cmat, partial, cnt, rows, cols);
    } else {
        cost_fused<<<BN * CBI, 256, 0, stream>>>(logits, boxes, ids, tboxes, img,
                                                 Cmat, nullptr, nullptr, rows, cols);
        assign_scan_kernel<<<BN, 512, 0, stream>>>(Cmat, rows, cols);
    }
}

// Round 6
// 135.887 us; speedup vs baseline: 1.7546x; 1.7546x over previous
//
#include <hip/hip_runtime.h>

// Problem constants (from reference setup_inputs): B=128, Q=500, C=80, T=64
#define BN 128
#define QN 500
#define CLS 80
#define TN 64
#define RPB 20                  // rows per cost block
#define CBI 25                  // cost blocks per image (500/20)
#define RPW 10                  // rows per wave (RPB/2), compile-time trip

typedef unsigned long long ull;

// Monotonic float->uint map: a < b  <=>  fkey(a) < fkey(b); equal <=> equal
__device__ __forceinline__ unsigned fkey(float x) {
    unsigned u = __float_as_uint(x);
    return (u & 0x80000000u) ? ~u : (u | 0x80000000u);
}
__device__ __forceinline__ ull kmin(ull a, ull b) { return a < b ? a : b; }  // branchless

// Full-wave (64-lane) u32 min via DPP: row_shr 1/2/4/8 + row_bcast15/31,
// identity 0xFFFFFFFF fed to invalid lanes; result in lane 63 -> readlane.
#define DPP_MIN_STEP(v, ctrl)                                                 \
    {                                                                         \
        unsigned _t = (unsigned)__builtin_amdgcn_update_dpp(                  \
            (int)0xFFFFFFFF, (int)(v), (ctrl), 0xf, 0xf, false);              \
        (v) = (_t < (v)) ? _t : (v);                                          \
    }
__device__ __forceinline__ unsigned wave_min_u32(unsigned v) {
    DPP_MIN_STEP(v, 0x111)   // row_shr:1
    DPP_MIN_STEP(v, 0x112)   // row_shr:2
    DPP_MIN_STEP(v, 0x114)   // row_shr:4
    DPP_MIN_STEP(v, 0x118)   // row_shr:8
    DPP_MIN_STEP(v, 0x142)   // row_bcast:15
    DPP_MIN_STEP(v, 0x143)   // row_bcast:31
    return (unsigned)__builtin_amdgcn_readlane((int)v, 63);
}

// Exact raveled argmin over 64 lanes holding (value hi, flat lo) pairs.
// Fast path: one 6-step u32 chain on hi; if the min value is held by a
// UNIQUE lane (overwhelming majority -- random float costs), the flat comes
// from a single variable-lane readlane. True value ties fall back to the
// second exact chain (min flat among tied lanes) == first-occurrence
// tie-break, identical semantics to the proven dual-chain version.
__device__ __forceinline__ ull wave_argmin(unsigned hi, unsigned lo) {
    const unsigned bv = wave_min_u32(hi);                  // min value (uniform)
    const ull tie = __ballot(hi == bv);
    unsigned fl;
    if (__popcll(tie) == 1) {                              // unique holder
        fl = (unsigned)__builtin_amdgcn_readlane(
            (int)lo, (int)(__ffsll((long long)tie) - 1));
    } else {                                               // rare: exact chain
        fl = wave_min_u32((hi == bv) ? lo : 0xFFFFFFFFu);
    }
    return ((ull)bv << 32) | fl;
}

// ---------------------------------------------------------------------------
// Kernel 1: cost matrix. Math BYTE-IDENTICAL to rounds 1/3 (same source
// positions -> same FMA contraction; fast-math / expression motion flips
// greedy ties -> round-5 failure). Wave-uniform divisions hoisted to LDS
// staging (bit-identical wherever computed; div never FMA-contracts).
// Logits stay direct per-element gathers (round-2's LDS staging measured
// ~5 us slower; round-4's fused fences measured 5x slower -- reverted).
// THIS round: 128-thread blocks, RPW=10 -- doubles per-thread independent
// logit-gather chains (cost was ~40% exposed-latency at 5-deep ILP; the
// unrolled loop lets the compiler hoist all 10 gathers). Same grid (3200),
// same RPB/CBI, same partial layout -- only the thread->row mapping changes.
// ---------------------------------------------------------------------------
__global__ __launch_bounds__(128) void cost_kernel(
    const float* __restrict__ logits,   // [B,Q,C]
    const float* __restrict__ boxes,    // [B,Q,4]
    const int*   __restrict__ ids,      // [B,T]
    const float* __restrict__ tboxes,   // [B,T,4]
    const float* __restrict__ img,      // [B,4]
    float* __restrict__ Cout,           // [B,Q,T]
    ull* __restrict__ partial)          // [B*CBI, 64] colmin keys, or null
{
    const int b    = blockIdx.x / CBI;
    const int blk  = blockIdx.x % CBI;
    const int wave = threadIdx.x >> 6;   // 0 or 1
    const int lane = threadIdx.x & 63;   // = column t
    const int q0   = blk * RPB;

    __shared__ float4 s_pb[RPB];        // raw pred boxes (this block's 20 rows)
    __shared__ float4 s_bn[RPB];        // normalized pred boxes (pb/im)
    __shared__ float4 s_tb[TN];         // raw target boxes
    __shared__ float4 s_tn[TN];         // normalized target boxes (tb/im)
    __shared__ int    s_id[TN];         // target class ids

    // Staging: wave 0 handles targets, wave 1 (lanes 0..19) handles pred rows.
    // Divisions here are bit-identical to the per-element ones they replace.
    if (wave == 0) {
        const float4 im = *(const float4*)(img + b * 4);
        const float4 tb = *(const float4*)(tboxes + (size_t)(b * TN + lane) * 4);
        s_tb[lane] = tb;
        float4 tn;
        tn.x = tb.x / im.x; tn.y = tb.y / im.y;
        tn.z = tb.z / im.z; tn.w = tb.w / im.w;
        s_tn[lane] = tn;
        s_id[lane] = ids[b * TN + lane];
    } else if (lane < RPB) {
        const float4 im = *(const float4*)(img + b * 4);
        const float4 pb = *(const float4*)(boxes + (size_t)(b * QN + q0 + lane) * 4);
        s_pb[lane] = pb;
        float4 bn;
        bn.x = pb.x / im.x; bn.y = pb.y / im.y;
        bn.z = pb.z / im.z; bn.w = pb.w / im.w;
        s_bn[lane] = bn;
    }
    __syncthreads();

    const float4 tb  = s_tb[lane];
    const float4 tn  = s_tn[lane];
    const int    id  = s_id[lane];
    // area_b: SAME expression/position as prior rounds (standalone mul,
    // multi-use, never contracted) -- preserves bit pattern.
    const float area_b = (tb.z - tb.x) * (tb.w - tb.y);

    ull colmin = ~0ull;
    #pragma unroll
    for (int rr = 0; rr < RPW; ++rr) {
        const int lr = wave * RPW + rr;       // local row 0..19
        const int q  = q0 + lr;
        const float x   = logits[(size_t)(b * QN + q) * CLS + id];
        const float4 pb = s_pb[lr];           // broadcast LDS read (no conflict)
        const float4 bn = s_bn[lr];

        float prob = 1.0f / (1.0f + expf(-x));
        float neg  = 0.75f * (prob * prob) * (-log1pf(1e-8f - prob));
        float pos  = 0.25f * ((1.0f - prob) * (1.0f - prob)) * (-logf(prob + 1e-8f));
        float cls  = pos - neg;

        float l1 = fabsf(bn.x - tn.x) + fabsf(bn.y - tn.y)
                 + fabsf(bn.z - tn.z) + fabsf(bn.w - tn.w);

        // area_a stays INSIDE the loop (single-use mul may be FMA-contracted
        // into `uni`; hoisting could change rounding -> greedy tie flip).
        float area_a = (pb.z - pb.x) * (pb.w - pb.y);
        float ltx = fmaxf(pb.x, tb.x), lty = fmaxf(pb.y, tb.y);
        float rbx = fminf(pb.z, tb.z), rby = fminf(pb.w, tb.w);
        float iw = fmaxf(rbx - ltx, 0.0f), ih = fmaxf(rby - lty, 0.0f);
        float inter = iw * ih;
        float uni   = area_a + area_b - inter;
        float iou   = inter / uni;
        float ex1 = fminf(pb.x, tb.x), ey1 = fminf(pb.y, tb.y);
        float ex2 = fmaxf(pb.z, tb.z), ey2 = fmaxf(pb.w, tb.w);
        float ew = fmaxf(ex2 - ex1, 0.0f), eh = fmaxf(ey2 - ey1, 0.0f);
        float enc = ew * eh;
        float giou = iou - (enc - uni) / enc;

        float cost = 5.0f * l1 + 2.0f * cls + 2.0f * (-giou);
        Cout[(size_t)(b * QN + q) * TN + lane] = cost;
        colmin = kmin(colmin, ((ull)fkey(cost) << 32) | (unsigned)(q * TN + lane));
    }

    if (partial) {
        __shared__ ull pk[2][TN];
        pk[wave][lane] = colmin;
        __syncthreads();
        if (wave == 0) {
            ull k = kmin(pk[0][lane], pk[1][lane]);
            partial[(size_t)blockIdx.x * TN + lane] = k;   // own slot: no race
        }
    }
}

// ---------------------------------------------------------------------------
// Greedy hot loop (single wave; lane = column) — proven in round 3.
// m1[j] = min alive key of column j. Per iteration: u32 value chain +
// ballot/ff1/readlane argmin (exact-tie fallback), per-lane 8-bit deadmask
// (lane l owns rows l+64k), cooperative column rescan on champion-row death
// (~4.6 per image).
// ---------------------------------------------------------------------------
__device__ __forceinline__ void greedy_loop(
    const float* __restrict__ Cb, ull m1in, int b, int lane,
    float* __restrict__ out_rows, float* __restrict__ out_cols)
{
    unsigned m1hi = (unsigned)(m1in >> 32);    // column-min value key
    unsigned m1lo = (unsigned)m1in;            // column-min flat index
    // lane l owns rows l, l+64, ..., l+448; bit k = row l+64k dead.
    // Rows 500..511 (rescan over-range; reads stay inside d_out) pre-dead:
    // 500 = 7*64+52 -> lanes 52..63 bit 7.
    unsigned deadmask = (lane >= 52) ? 0x80u : 0u;

    int my_i = 0, my_j = 0;             // lane t captures iteration t's result

    for (int t = 0; t < TN; ++t) {
        const ull best = wave_argmin(m1hi, m1lo);          // uniform
        const unsigned flat = (unsigned)best;
        const int i = (int)(flat >> 6);                    // SGPR
        const int j = (int)(flat & 63u);                   // SGPR
        if (lane == t) { my_i = i; my_j = j; }             // cmp + 2 cndmask

        if (lane == j) { m1hi = 0xFFFFFFFFu; m1lo = 0xFFFFFFFFu; }  // retire col
        deadmask |= (lane == (i & 63)) ? (1u << (i >> 6)) : 0u;     // retire row

        // stale champions (argmin row == i) rescan; INF m1 auto-excluded
        // (lo=0xFFFFFFFF -> argrow 0x3FFFFFF never equals i<=511).
        ull need = __ballot((m1lo >> 6) == (unsigned)i);
        while (need) {                                     // ~4.6 total/image
            const int jr = (int)(__ffsll((long long)need) - 1);  // lane==column
            need &= need - 1;
            ull nb = ~0ull;
            #pragma unroll
            for (int k8 = 0; k8 < 8; ++k8) {
                int r = lane + (k8 << 6);
                float vv = Cb[(size_t)r * TN + jr];
                bool dead = (deadmask >> k8) & 1u;
                ull kk = dead ? ~0ull
                              : (((ull)fkey(vv) << 32) | (unsigned)(r * TN + jr));
                nb = kmin(nb, kk);
            }
            const ull nbest = wave_argmin((unsigned)(nb >> 32), (unsigned)nb);
            if (lane == jr) { m1hi = (unsigned)(nbest >> 32); m1lo = (unsigned)nbest; }
        }
    }

    out_rows[b * TN + lane] = (float)my_i;                 // coalesced
    out_cols[b * TN + lane] = (float)my_j;
}

// Table path: 512 threads; 8 waves cooperatively reduce the image's 25
// partial rows (coalesced 512 B row loads), LDS merge, wave 0 runs greedy.
__global__ __launch_bounds__(512, 1) void assign_table_kernel(
    const float* __restrict__ Cmat, const ull* __restrict__ partial,
    float* __restrict__ out_rows, float* __restrict__ out_cols)
{
    const int b    = blockIdx.x;
    const int wave = threadIdx.x >> 6;
    const int lane = threadIdx.x & 63;
    const float* Cb = Cmat + (size_t)b * QN * TN;
    const ull* pt = partial + (size_t)b * CBI * TN;

    __shared__ ull smin[8][TN];         // 4 KB
    {
        ull k = ~0ull;
        #pragma unroll
        for (int p = 0; p < 4; ++p) {   // rows wave, wave+8, wave+16, wave+24
            const int row = wave + 8 * p;
            if (row < CBI) k = kmin(k, pt[(size_t)row * TN + lane]);
        }
        smin[wave][lane] = k;
    }
    __syncthreads();
    if (wave != 0) return;

    ull m1 = ~0ull;
    #pragma unroll
    for (int w = 0; w < 8; ++w) m1 = kmin(m1, smin[w][lane]);

    greedy_loop(Cb, m1, b, lane, out_rows, out_cols);
}

// Fallback path (no workspace): float4 init, branchless min, LDS merge.
// Wave w, lane l: g=l>>4 owns rows w*63+g+4k (k<16), c4=l&15 owns cols
// [4c4,4c4+4) -> 16 independent float4 loads/thread. Proven in round 9.
__global__ __launch_bounds__(512, 1) void assign_scan_kernel(
    const float* __restrict__ Cmat,
    float* __restrict__ out_rows, float* __restrict__ out_cols)
{
    const int b    = blockIdx.x;
    const int wave = threadIdx.x >> 6;
    const int lane = threadIdx.x & 63;
    const float* Cb = Cmat + (size_t)b * QN * TN;

    __shared__ ull smin[32][TN];        // 16 KB

    {
        const int g  = lane >> 4;
        const int c4 = (lane & 15) << 2;
        const int rbeg = wave * 63 + g;
        ull mc0 = ~0ull, mc1 = ~0ull, mc2 = ~0ull, mc3 = ~0ull;
        #pragma unroll
        for (int k = 0; k < 16; ++k) {
            const int r = rbeg + 4 * k;            // <= 504: inside d_out
            const float4 v = *(const float4*)(Cb + (size_t)r * TN + c4);
            const bool ok = (r < QN);
            const unsigned fb = (unsigned)(r * TN + c4);
            mc0 = kmin(mc0, ok ? (((ull)fkey(v.x) << 32) | (fb + 0)) : ~0ull);
            mc1 = kmin(mc1, ok ? (((ull)fkey(v.y) << 32) | (fb + 1)) : ~0ull);
            mc2 = kmin(mc2, ok ? (((ull)fkey(v.z) << 32) | (fb + 2)) : ~0ull);
            mc3 = kmin(mc3, ok ? (((ull)fkey(v.w) << 32) | (fb + 3)) : ~0ull);
        }
        const int lrow = (wave << 2) | g;
        smin[lrow][c4 + 0] = mc0;
        smin[lrow][c4 + 1] = mc1;
        smin[lrow][c4 + 2] = mc2;
        smin[lrow][c4 + 3] = mc3;
    }
    __syncthreads();
    if (wave != 0) return;

    ull m1 = ~0ull;
    #pragma unroll
    for (int w = 0; w < 32; ++w) m1 = kmin(m1, smin[w][lane]);

    greedy_loop(Cb, m1, b, lane, out_rows, out_cols);
}

extern "C" void kernel_launch(void* const* d_in, const int* in_sizes, int n_in,
                              void* d_out, int out_size, void* d_ws, size_t ws_size,
                              hipStream_t stream) {
    const float* logits = (const float*)d_in[0];   // [128,500,80]
    const float* boxes  = (const float*)d_in[1];   // [128,500,4]
    const int*   ids    = (const int*)d_in[2];     // [128,64]
    const float* tboxes = (const float*)d_in[3];   // [128,64,4]
    const float* img    = (const float*)d_in[4];   // [128,4]

    float* out  = (float*)d_out;
    float* Cmat = out;                              // 128*500*64 = 4,096,000
    float* rows = out + (size_t)BN * QN * TN;       // +8192
    float* cols = rows + BN * TN;                   // +8192

    const size_t table_bytes = (size_t)BN * CBI * TN * sizeof(ull);  // 1.6 MB
    const bool use_table = (ws_size >= table_bytes);                  // host-constant
    ull* partial = use_table ? (ull*)d_ws : nullptr;

    cost_kernel<<<BN * CBI, 128, 0, stream>>>(logits, boxes, ids, tboxes, img,
                                              Cmat, partial);

    if (use_table)
        assign_table_kernel<<<BN, 512, 0, stream>>>(Cmat, partial, rows, cols);
    else
        assign_scan_kernel<<<BN, 512, 0, stream>>>(Cmat, rows, cols);
}

// Round 7
// 132.944 us; speedup vs baseline: 1.7935x; 1.0221x over previous
//
#include <hip/hip_runtime.h>

// Problem constants (from reference setup_inputs): B=128, Q=500, C=80, T=64
#define BN 128
#define QN 500
#define CLS 80
#define TN 64
#define RPB 20                  // rows per cost block
#define CBI 25                  // cost blocks per image (500/20)
#define RPW 5                   // rows per wave (RPB/4), compile-time trip

typedef unsigned long long ull;

// Monotonic float->uint map: a < b  <=>  fkey(a) < fkey(b); equal <=> equal
__device__ __forceinline__ unsigned fkey(float x) {
    unsigned u = __float_as_uint(x);
    return (u & 0x80000000u) ? ~u : (u | 0x80000000u);
}
__device__ __forceinline__ ull kmin(ull a, ull b) { return a < b ? a : b; }  // branchless

// Full-wave (64-lane) u32 min via DPP: row_shr 1/2/4/8 + row_bcast15/31,
// identity 0xFFFFFFFF fed to invalid lanes; result in lane 63 -> readlane.
#define DPP_MIN_STEP(v, ctrl)                                                 \
    {                                                                         \
        unsigned _t = (unsigned)__builtin_amdgcn_update_dpp(                  \
            (int)0xFFFFFFFF, (int)(v), (ctrl), 0xf, 0xf, false);              \
        (v) = (_t < (v)) ? _t : (v);                                          \
    }
__device__ __forceinline__ unsigned wave_min_u32(unsigned v) {
    DPP_MIN_STEP(v, 0x111)   // row_shr:1
    DPP_MIN_STEP(v, 0x112)   // row_shr:2
    DPP_MIN_STEP(v, 0x114)   // row_shr:4
    DPP_MIN_STEP(v, 0x118)   // row_shr:8
    DPP_MIN_STEP(v, 0x142)   // row_bcast:15
    DPP_MIN_STEP(v, 0x143)   // row_bcast:31
    return (unsigned)__builtin_amdgcn_readlane((int)v, 63);
}

// Exact raveled argmin over 64 lanes holding (value hi, flat lo) pairs.
// Fast path: one 6-step u32 chain on hi; if the min value is held by a
// UNIQUE lane (overwhelming majority -- random float costs), the flat comes
// from a single variable-lane readlane. True value ties fall back to the
// second exact chain (min flat among tied lanes) == first-occurrence
// tie-break, identical semantics to the proven dual-chain version.
__device__ __forceinline__ ull wave_argmin(unsigned hi, unsigned lo) {
    const unsigned bv = wave_min_u32(hi);                  // min value (uniform)
    const ull tie = __ballot(hi == bv);
    unsigned fl;
    if (__popcll(tie) == 1) {                              // unique holder
        fl = (unsigned)__builtin_amdgcn_readlane(
            (int)lo, (int)(__ffsll((long long)tie) - 1));
    } else {                                               // rare: exact chain
        fl = wave_min_u32((hi == bv) ? lo : 0xFFFFFFFFu);
    }
    return ((ull)bv << 32) | fl;
}

// ---------------------------------------------------------------------------
// Kernel 1: cost matrix — round-3 configuration (best measured: 133.9 us).
// Math BYTE-IDENTICAL to the proven kernels (same source positions -> same
// FMA contraction; fast-math / expression motion flips greedy ties).
// Wave-uniform divisions hoisted to LDS staging (bit-identical wherever
// computed; div never FMA-contracts). Logits stay direct per-element
// gathers. Measured dead ends, do not revisit: logits LDS staging (r2, -5us),
// last-block fusion fences (r4, 5x), RPW=10/128-thread ILP (r6, null),
// class-dedup (paper: <2us gain for 4-barrier risk).
// ---------------------------------------------------------------------------
__global__ __launch_bounds__(256) void cost_kernel(
    const float* __restrict__ logits,   // [B,Q,C]
    const float* __restrict__ boxes,    // [B,Q,4]
    const int*   __restrict__ ids,      // [B,T]
    const float* __restrict__ tboxes,   // [B,T,4]
    const float* __restrict__ img,      // [B,4]
    float* __restrict__ Cout,           // [B,Q,T]
    ull* __restrict__ partial)          // [B*CBI, 64] colmin keys, or null
{
    const int b    = blockIdx.x / CBI;
    const int blk  = blockIdx.x % CBI;
    const int wave = threadIdx.x >> 6;
    const int lane = threadIdx.x & 63;   // = column t
    const int q0   = blk * RPB;

    __shared__ float4 s_pb[RPB];        // raw pred boxes (this block's 20 rows)
    __shared__ float4 s_bn[RPB];        // normalized pred boxes (pb/im)
    __shared__ float4 s_tb[TN];         // raw target boxes
    __shared__ float4 s_tn[TN];         // normalized target boxes (tb/im)
    __shared__ int    s_id[TN];         // target class ids

    // Staging: wave 0 handles targets, wave 1 (lanes 0..19) handles pred rows.
    // Divisions here are bit-identical to the per-element ones they replace.
    if (wave == 0) {
        const float4 im = *(const float4*)(img + b * 4);
        const float4 tb = *(const float4*)(tboxes + (size_t)(b * TN + lane) * 4);
        s_tb[lane] = tb;
        float4 tn;
        tn.x = tb.x / im.x; tn.y = tb.y / im.y;
        tn.z = tb.z / im.z; tn.w = tb.w / im.w;
        s_tn[lane] = tn;
        s_id[lane] = ids[b * TN + lane];
    } else if (wave == 1 && lane < RPB) {
        const float4 im = *(const float4*)(img + b * 4);
        const float4 pb = *(const float4*)(boxes + (size_t)(b * QN + q0 + lane) * 4);
        s_pb[lane] = pb;
        float4 bn;
        bn.x = pb.x / im.x; bn.y = pb.y / im.y;
        bn.z = pb.z / im.z; bn.w = pb.w / im.w;
        s_bn[lane] = bn;
    }
    __syncthreads();

    const float4 tb  = s_tb[lane];
    const float4 tn  = s_tn[lane];
    const int    id  = s_id[lane];
    // area_b: SAME expression/position as prior rounds (standalone mul,
    // multi-use, never contracted) -- preserves bit pattern.
    const float area_b = (tb.z - tb.x) * (tb.w - tb.y);

    ull colmin = ~0ull;
    #pragma unroll
    for (int rr = 0; rr < RPW; ++rr) {
        const int lr = wave * RPW + rr;       // local row 0..19
        const int q  = q0 + lr;
        const float x   = logits[(size_t)(b * QN + q) * CLS + id];
        const float4 pb = s_pb[lr];           // broadcast LDS read (no conflict)
        const float4 bn = s_bn[lr];

        float prob = 1.0f / (1.0f + expf(-x));
        float neg  = 0.75f * (prob * prob) * (-log1pf(1e-8f - prob));
        float pos  = 0.25f * ((1.0f - prob) * (1.0f - prob)) * (-logf(prob + 1e-8f));
        float cls  = pos - neg;

        float l1 = fabsf(bn.x - tn.x) + fabsf(bn.y - tn.y)
                 + fabsf(bn.z - tn.z) + fabsf(bn.w - tn.w);

        // area_a stays INSIDE the loop (single-use mul may be FMA-contracted
        // into `uni`; hoisting could change rounding -> greedy tie flip).
        float area_a = (pb.z - pb.x) * (pb.w - pb.y);
        float ltx = fmaxf(pb.x, tb.x), lty = fmaxf(pb.y, tb.y);
        float rbx = fminf(pb.z, tb.z), rby = fminf(pb.w, tb.w);
        float iw = fmaxf(rbx - ltx, 0.0f), ih = fmaxf(rby - lty, 0.0f);
        float inter = iw * ih;
        float uni   = area_a + area_b - inter;
        float iou   = inter / uni;
        float ex1 = fminf(pb.x, tb.x), ey1 = fminf(pb.y, tb.y);
        float ex2 = fmaxf(pb.z, tb.z), ey2 = fmaxf(pb.w, tb.w);
        float ew = fmaxf(ex2 - ex1, 0.0f), eh = fmaxf(ey2 - ey1, 0.0f);
        float enc = ew * eh;
        float giou = iou - (enc - uni) / enc;

        float cost = 5.0f * l1 + 2.0f * cls + 2.0f * (-giou);
        Cout[(size_t)(b * QN + q) * TN + lane] = cost;
        colmin = kmin(colmin, ((ull)fkey(cost) << 32) | (unsigned)(q * TN + lane));
    }

    if (partial) {
        __shared__ ull pk[4][TN];
        pk[wave][lane] = colmin;
        __syncthreads();
        if (wave == 0) {
            ull k = kmin(kmin(pk[0][lane], pk[1][lane]),
                         kmin(pk[2][lane], pk[3][lane]));
            partial[(size_t)blockIdx.x * TN + lane] = k;   // own slot: no race
        }
    }
}

// ---------------------------------------------------------------------------
// Greedy hot loop (single wave; lane = column) — proven in round 3.
// m1[j] = min alive key of column j. Per iteration: u32 value chain +
// ballot/ff1/readlane argmin (exact-tie fallback), per-lane 8-bit deadmask
// (lane l owns rows l+64k), cooperative column rescan on champion-row death
// (~4.6 per image).
// ---------------------------------------------------------------------------
__device__ __forceinline__ void greedy_loop(
    const float* __restrict__ Cb, ull m1in, int b, int lane,
    float* __restrict__ out_rows, float* __restrict__ out_cols)
{
    unsigned m1hi = (unsigned)(m1in >> 32);    // column-min value key
    unsigned m1lo = (unsigned)m1in;            // column-min flat index
    // lane l owns rows l, l+64, ..., l+448; bit k = row l+64k dead.
    // Rows 500..511 (rescan over-range; reads stay inside d_out) pre-dead:
    // 500 = 7*64+52 -> lanes 52..63 bit 7.
    unsigned deadmask = (lane >= 52) ? 0x80u : 0u;

    int my_i = 0, my_j = 0;             // lane t captures iteration t's result

    for (int t = 0; t < TN; ++t) {
        const ull best = wave_argmin(m1hi, m1lo);          // uniform
        const unsigned flat = (unsigned)best;
        const int i = (int)(flat >> 6);                    // SGPR
        const int j = (int)(flat & 63u);                   // SGPR
        if (lane == t) { my_i = i; my_j = j; }             // cmp + 2 cndmask

        if (lane == j) { m1hi = 0xFFFFFFFFu; m1lo = 0xFFFFFFFFu; }  // retire col
        deadmask |= (lane == (i & 63)) ? (1u << (i >> 6)) : 0u;     // retire row

        // stale champions (argmin row == i) rescan; INF m1 auto-excluded
        // (lo=0xFFFFFFFF -> argrow 0x3FFFFFF never equals i<=511).
        ull need = __ballot((m1lo >> 6) == (unsigned)i);
        while (need) {                                     // ~4.6 total/image
            const int jr = (int)(__ffsll((long long)need) - 1);  // lane==column
            need &= need - 1;
            ull nb = ~0ull;
            #pragma unroll
            for (int k8 = 0; k8 < 8; ++k8) {
                int r = lane + (k8 << 6);
                float vv = Cb[(size_t)r * TN + jr];
                bool dead = (deadmask >> k8) & 1u;
                ull kk = dead ? ~0ull
                              : (((ull)fkey(vv) << 32) | (unsigned)(r * TN + jr));
                nb = kmin(nb, kk);
            }
            const ull nbest = wave_argmin((unsigned)(nb >> 32), (unsigned)nb);
            if (lane == jr) { m1hi = (unsigned)(nbest >> 32); m1lo = (unsigned)nbest; }
        }
    }

    out_rows[b * TN + lane] = (float)my_i;                 // coalesced
    out_cols[b * TN + lane] = (float)my_j;
}

// Table path: 512 threads; 8 waves cooperatively reduce the image's 25
// partial rows (coalesced 512 B row loads), LDS merge, wave 0 runs greedy.
__global__ __launch_bounds__(512, 1) void assign_table_kernel(
    const float* __restrict__ Cmat, const ull* __restrict__ partial,
    float* __restrict__ out_rows, float* __restrict__ out_cols)
{
    const int b    = blockIdx.x;
    const int wave = threadIdx.x >> 6;
    const int lane = threadIdx.x & 63;
    const float* Cb = Cmat + (size_t)b * QN * TN;
    const ull* pt = partial + (size_t)b * CBI * TN;

    __shared__ ull smin[8][TN];         // 4 KB
    {
        ull k = ~0ull;
        #pragma unroll
        for (int p = 0; p < 4; ++p) {   // rows wave, wave+8, wave+16, wave+24
            const int row = wave + 8 * p;
            if (row < CBI) k = kmin(k, pt[(size_t)row * TN + lane]);
        }
        smin[wave][lane] = k;
    }
    __syncthreads();
    if (wave != 0) return;

    ull m1 = ~0ull;
    #pragma unroll
    for (int w = 0; w < 8; ++w) m1 = kmin(m1, smin[w][lane]);

    greedy_loop(Cb, m1, b, lane, out_rows, out_cols);
}

// Fallback path (no workspace): float4 init, branchless min, LDS merge.
// Wave w, lane l: g=l>>4 owns rows w*63+g+4k (k<16), c4=l&15 owns cols
// [4c4,4c4+4) -> 16 independent float4 loads/thread. Proven in round 9.
__global__ __launch_bounds__(512, 1) void assign_scan_kernel(
    const float* __restrict__ Cmat,
    float* __restrict__ out_rows, float* __restrict__ out_cols)
{
    const int b    = blockIdx.x;
    const int wave = threadIdx.x >> 6;
    const int lane = threadIdx.x & 63;
    const float* Cb = Cmat + (size_t)b * QN * TN;

    __shared__ ull smin[32][TN];        // 16 KB

    {
        const int g  = lane >> 4;
        const int c4 = (lane & 15) << 2;
        const int rbeg = wave * 63 + g;
        ull mc0 = ~0ull, mc1 = ~0ull, mc2 = ~0ull, mc3 = ~0ull;
        #pragma unroll
        for (int k = 0; k < 16; ++k) {
            const int r = rbeg + 4 * k;            // <= 504: inside d_out
            const float4 v = *(const float4*)(Cb + (size_t)r * TN + c4);
            const bool ok = (r < QN);
            const unsigned fb = (unsigned)(r * TN + c4);
            mc0 = kmin(mc0, ok ? (((ull)fkey(v.x) << 32) | (fb + 0)) : ~0ull);
            mc1 = kmin(mc1, ok ? (((ull)fkey(v.y) << 32) | (fb + 1)) : ~0ull);
            mc2 = kmin(mc2, ok ? (((ull)fkey(v.z) << 32) | (fb + 2)) : ~0ull);
            mc3 = kmin(mc3, ok ? (((ull)fkey(v.w) << 32) | (fb + 3)) : ~0ull);
        }
        const int lrow = (wave << 2) | g;
        smin[lrow][c4 + 0] = mc0;
        smin[lrow][c4 + 1] = mc1;
        smin[lrow][c4 + 2] = mc2;
        smin[lrow][c4 + 3] = mc3;
    }
    __syncthreads();
    if (wave != 0) return;

    ull m1 = ~0ull;
    #pragma unroll
    for (int w = 0; w < 32; ++w) m1 = kmin(m1, smin[w][lane]);

    greedy_loop(Cb, m1, b, lane, out_rows, out_cols);
}

extern "C" void kernel_launch(void* const* d_in, const int* in_sizes, int n_in,
                              void* d_out, int out_size, void* d_ws, size_t ws_size,
                              hipStream_t stream) {
    const float* logits = (const float*)d_in[0];   // [128,500,80]
    const float* boxes  = (const float*)d_in[1];   // [128,500,4]
    const int*   ids    = (const int*)d_in[2];     // [128,64]
    const float* tboxes = (const float*)d_in[3];   // [128,64,4]
    const float* img    = (const float*)d_in[4];   // [128,4]

    float* out  = (float*)d_out;
    float* Cmat = out;                              // 128*500*64 = 4,096,000
    float* rows = out + (size_t)BN * QN * TN;       // +8192
    float* cols = rows + BN * TN;                   // +8192

    const size_t table_bytes = (size_t)BN * CBI * TN * sizeof(ull);  // 1.6 MB
    const bool use_table = (ws_size >= table_bytes);                  // host-constant
    ull* partial = use_table ? (ull*)d_ws : nullptr;

    cost_kernel<<<BN * CBI, 256, 0, stream>>>(logits, boxes, ids, tboxes, img,
                                              Cmat, partial);

    if (use_table)
        assign_table_kernel<<<BN, 512, 0, stream>>>(Cmat, partial, rows, cols);
    else
        assign_scan_kernel<<<BN, 512, 0, stream>>>(Cmat, rows, cols);
}